// Round 12
// baseline (135.479 us; speedup 1.0000x reference)
//
#include <hip/hip_runtime.h>
#include <hip/hip_fp16.h>
#include <math.h>

#define IN_DIM 256
#define L1_DIM 16
#define N_ETYPE_MAX 1000
#define NBLOCKS 512
#define NTHREADS 512

typedef _Float16 f16x8 __attribute__((ext_vector_type(8)));
typedef float f32x4 __attribute__((ext_vector_type(4)));

union F4H { float4 f; __half2 h[4]; };

// Single fused kernel, 512 blocks x 512 threads.
// Co-residency guaranteed: launch_bounds(512,4) => <=128 VGPR; 62.5 KB LDS
// => 2 blocks/CU; 2 x 256 CU = 512 = grid size. Manual device-scope barrier
// (release/acquire agent-scope atomics handle cross-XCD L2 via wbl2/inv).
// Phase 0: w_l2 f32 -> interleaved fp16 LDS table (per block, no global
//          intermediate, no separate convert dispatch).
// Phase 1: proj GEMM mfma_f32_16x16x32_f16, one wave per 16-row block.
// Barrier.
// Phase 2: edge scoring, 2 lanes/edge (R8 structure, best measured).
__global__ __launch_bounds__(NTHREADS, 4) void fused_kernel(
    const float* __restrict__ z,
    const float* __restrict__ w1,     // [256][16]
    const float* __restrict__ w2,
    const float* __restrict__ w1_l2,  // [1000][16]
    const float* __restrict__ w2_l2,
    const int* __restrict__ edge_index,  // [2][n_edges]
    const int* __restrict__ edge_type,   // [n_edges]
    __half* __restrict__ h1,          // [n_nodes][16] fp16 (ws)
    __half* __restrict__ h2,
    unsigned int* __restrict__ cnt,   // barrier counter (ws, memset to 0)
    float* __restrict__ out,
    int n_nodes, int n_edges, int n_l2) {
  __shared__ __align__(16) __half wl[N_ETYPE_MAX * 32];  // 62.5 KB

  const int tid = (int)threadIdx.x;
  const int bid = (int)blockIdx.x;

  // ---- phase 0: stage interleaved level-2 fp16 table into LDS ----
  for (int i = tid; i < n_l2; i += NTHREADS) {
    int t = i >> 4;
    int j = i & 15;
    wl[t * 32 + j]      = __float2half(w1_l2[i]);
    wl[t * 32 + 16 + j] = __float2half(w2_l2[i]);
  }

  // ---- phase 1: proj (one wave per 16-row block) ----
  const int lane = tid & 63;
  const int wv   = tid >> 6;      // 0..7
  const int r    = lane & 15;     // A row-in-tile / B col / D col
  const int q    = lane >> 4;     // k-subgroup 0..3

  // B fragments: k = 32s + 8q + j, col = r
  f16x8 bf1[8], bf2[8];
#pragma unroll
  for (int s = 0; s < 8; ++s) {
#pragma unroll
    for (int j = 0; j < 8; ++j) {
      int k = 32 * s + 8 * q + j;
      bf1[s][j] = (_Float16)w1[k * L1_DIM + r];
      bf2[s][j] = (_Float16)w2[k * L1_DIM + r];
    }
  }

  const int gw = bid * 8 + wv;               // global wave id, 0..4095
  const int n_rb = (n_nodes + 15) >> 4;      // 16-row blocks: 3125
  for (int rb = gw; rb < n_rb; rb += NBLOCKS * 8) {
    int arow = rb * 16 + r;
    int ar = arow < n_nodes ? arow : (n_nodes - 1);
    const float* zrow = z + (size_t)ar * IN_DIM + 8 * q;

    f32x4 acc1 = {0.f, 0.f, 0.f, 0.f};
    f32x4 acc2 = {0.f, 0.f, 0.f, 0.f};

#pragma unroll
    for (int s = 0; s < 8; ++s) {
      float4 lo = *reinterpret_cast<const float4*>(zrow + 32 * s);
      float4 hi = *reinterpret_cast<const float4*>(zrow + 32 * s + 4);
      f16x8 af;
      af[0] = (_Float16)lo.x; af[1] = (_Float16)lo.y;
      af[2] = (_Float16)lo.z; af[3] = (_Float16)lo.w;
      af[4] = (_Float16)hi.x; af[5] = (_Float16)hi.y;
      af[6] = (_Float16)hi.z; af[7] = (_Float16)hi.w;
      acc1 = __builtin_amdgcn_mfma_f32_16x16x32_f16(af, bf1[s], acc1, 0, 0, 0);
      acc2 = __builtin_amdgcn_mfma_f32_16x16x32_f16(af, bf2[s], acc2, 0, 0, 0);
    }

    // D layout: col = r, row = 4q + i
#pragma unroll
    for (int i = 0; i < 4; ++i) {
      int node = rb * 16 + 4 * q + i;
      if (node < n_nodes) {
        h1[(size_t)node * L1_DIM + r] = __float2half(fmaxf(acc1[i], 0.f));
        h2[(size_t)node * L1_DIM + r] = __float2half(fmaxf(acc2[i], 0.f));
      }
    }
  }

  // ---- manual grid barrier (device-scope, cross-XCD safe) ----
  __syncthreads();
  if (tid == 0) {
    // release: waits vm, writes back this XCD's L2, then bumps the counter
    __hip_atomic_fetch_add(cnt, 1u, __ATOMIC_RELEASE, __HIP_MEMORY_SCOPE_AGENT);
    // acquire-spin: sees all 512 releases, then invalidates local caches
    while (__hip_atomic_load(cnt, __ATOMIC_ACQUIRE, __HIP_MEMORY_SCOPE_AGENT)
           < (unsigned int)NBLOCKS) {
      __builtin_amdgcn_s_sleep(8);
    }
  }
  __syncthreads();

  // ---- phase 2: edge (R8 structure) ----
  const int eq   = tid & 1;
  const int pair = tid >> 1;          // 0..255
  const int estride = NBLOCKS * (NTHREADS / 2);

  for (int e = bid * (NTHREADS / 2) + pair; e < n_edges; e += estride) {
    int src = edge_index[e];
    int dst = edge_index[n_edges + e];
    int t   = edge_type[e];

    F4H a, b, u, v;
    a.f = *reinterpret_cast<const float4*>(h1 + (size_t)src * L1_DIM + eq * 8);
    b.f = *reinterpret_cast<const float4*>(h2 + (size_t)dst * L1_DIM + eq * 8);
    u.f = *reinterpret_cast<const float4*>(wl + t * 32 + eq * 8);
    v.f = *reinterpret_cast<const float4*>(wl + t * 32 + 16 + eq * 8);

    float s = 0.f;
#if __has_builtin(__builtin_amdgcn_fdot2)
#pragma unroll
    for (int p = 0; p < 4; ++p) {
      s = __builtin_amdgcn_fdot2(a.h[p], u.h[p], s, false);
      s = __builtin_amdgcn_fdot2(b.h[p], v.h[p], s, false);
    }
#else
#pragma unroll
    for (int p = 0; p < 4; ++p) {
      float2 af = __half22float2(a.h[p]), uf = __half22float2(u.h[p]);
      float2 bf = __half22float2(b.h[p]), vf = __half22float2(v.h[p]);
      s = fmaf(af.x, uf.x, s); s = fmaf(af.y, uf.y, s);
      s = fmaf(bf.x, vf.x, s); s = fmaf(bf.y, vf.y, s);
    }
#endif

    s += __shfl_xor(s, 1);
    if (eq == 0) {
      out[e] = 1.0f / (1.0f + __expf(-s));
    }
  }
}

extern "C" void kernel_launch(void* const* d_in, const int* in_sizes, int n_in,
                              void* d_out, int out_size, void* d_ws, size_t ws_size,
                              hipStream_t stream) {
  const float* z      = (const float*)d_in[0];
  const int* edge_idx = (const int*)d_in[1];
  const int* edge_typ = (const int*)d_in[2];
  const float* w1_l1  = (const float*)d_in[3];
  const float* w1_l2  = (const float*)d_in[4];
  const float* w2_l1  = (const float*)d_in[5];
  const float* w2_l2  = (const float*)d_in[6];
  float* out = (float*)d_out;

  int n_nodes = in_sizes[0] / IN_DIM;
  int n_edges = in_sizes[2];
  int n_l2    = in_sizes[4];          // 1000*16

  __half* h1 = (__half*)d_ws;
  __half* h2 = h1 + (size_t)n_nodes * L1_DIM;
  unsigned int* cnt = (unsigned int*)(h2 + (size_t)n_nodes * L1_DIM);

  // reset barrier counter (graph-capturable memset node)
  hipMemsetAsync(cnt, 0, sizeof(unsigned int), stream);

  fused_kernel<<<NBLOCKS, NTHREADS, 0, stream>>>(
      z, w1_l1, w2_l1, w1_l2, w2_l2, edge_idx, edge_typ,
      h1, h2, cnt, out, n_nodes, n_edges, n_l2);
}

// Round 13
// 91.430 us; speedup vs baseline: 1.4818x; 1.4818x over previous
//
#include <hip/hip_runtime.h>
#include <hip/hip_fp16.h>
#include <math.h>

#define IN_DIM 256
#define L1_DIM 16
#define N_ETYPE_MAX 1000
#define NBLOCKS 512
#define NTHREADS 512

typedef _Float16 f16x8 __attribute__((ext_vector_type(8)));
typedef float f32x4 __attribute__((ext_vector_type(4)));

union F4H { float4 f; __half2 h[4]; };

// Single fused kernel, 512 blocks x 512 threads (2 blocks/CU guaranteed:
// launch_bounds(512,4) => <=128 VGPR; 62.5 KB LDS; 2 x 256 CU = 512 = grid).
// R13: barrier spin is RELAXED (no invalidate per poll) + ONE acquire at
// exit. R12's per-poll ACQUIRE invalidated L2 chip-wide during the spin and
// destroyed cache residency for the still-working blocks (530 GB/s, 140us).
__global__ __launch_bounds__(NTHREADS, 4) void fused_kernel(
    const float* __restrict__ z,
    const float* __restrict__ w1,     // [256][16]
    const float* __restrict__ w2,
    const float* __restrict__ w1_l2,  // [1000][16]
    const float* __restrict__ w2_l2,
    const int* __restrict__ edge_index,  // [2][n_edges]
    const int* __restrict__ edge_type,   // [n_edges]
    __half* __restrict__ h1,          // [n_nodes][16] fp16 (ws)
    __half* __restrict__ h2,
    unsigned int* __restrict__ cnt,   // barrier counter (ws, memset to 0)
    float* __restrict__ out,
    int n_nodes, int n_edges, int n_l2) {
  __shared__ __align__(16) __half wl[N_ETYPE_MAX * 32];  // 62.5 KB

  const int tid = (int)threadIdx.x;
  const int bid = (int)blockIdx.x;

  // ---- phase 0: stage interleaved level-2 fp16 table into LDS ----
  for (int i = tid; i < n_l2; i += NTHREADS) {
    int t = i >> 4;
    int j = i & 15;
    wl[t * 32 + j]      = __float2half(w1_l2[i]);
    wl[t * 32 + 16 + j] = __float2half(w2_l2[i]);
  }

  // ---- phase 1: proj (one wave per 16-row block) ----
  const int lane = tid & 63;
  const int wv   = tid >> 6;      // 0..7
  const int r    = lane & 15;     // A row-in-tile / B col / D col
  const int q    = lane >> 4;     // k-subgroup 0..3

  // B fragments: k = 32s + 8q + j, col = r
  f16x8 bf1[8], bf2[8];
#pragma unroll
  for (int s = 0; s < 8; ++s) {
#pragma unroll
    for (int j = 0; j < 8; ++j) {
      int k = 32 * s + 8 * q + j;
      bf1[s][j] = (_Float16)w1[k * L1_DIM + r];
      bf2[s][j] = (_Float16)w2[k * L1_DIM + r];
    }
  }

  const int gw = bid * 8 + wv;               // global wave id, 0..4095
  const int n_rb = (n_nodes + 15) >> 4;      // 16-row blocks: 3125
  for (int rb = gw; rb < n_rb; rb += NBLOCKS * 8) {
    int arow = rb * 16 + r;
    int ar = arow < n_nodes ? arow : (n_nodes - 1);
    const float* zrow = z + (size_t)ar * IN_DIM + 8 * q;

    f32x4 acc1 = {0.f, 0.f, 0.f, 0.f};
    f32x4 acc2 = {0.f, 0.f, 0.f, 0.f};

#pragma unroll
    for (int s = 0; s < 8; ++s) {
      float4 lo = *reinterpret_cast<const float4*>(zrow + 32 * s);
      float4 hi = *reinterpret_cast<const float4*>(zrow + 32 * s + 4);
      f16x8 af;
      af[0] = (_Float16)lo.x; af[1] = (_Float16)lo.y;
      af[2] = (_Float16)lo.z; af[3] = (_Float16)lo.w;
      af[4] = (_Float16)hi.x; af[5] = (_Float16)hi.y;
      af[6] = (_Float16)hi.z; af[7] = (_Float16)hi.w;
      acc1 = __builtin_amdgcn_mfma_f32_16x16x32_f16(af, bf1[s], acc1, 0, 0, 0);
      acc2 = __builtin_amdgcn_mfma_f32_16x16x32_f16(af, bf2[s], acc2, 0, 0, 0);
    }

    // D layout: col = r, row = 4q + i
#pragma unroll
    for (int i = 0; i < 4; ++i) {
      int node = rb * 16 + 4 * q + i;
      if (node < n_nodes) {
        h1[(size_t)node * L1_DIM + r] = __float2half(fmaxf(acc1[i], 0.f));
        h2[(size_t)node * L1_DIM + r] = __float2half(fmaxf(acc2[i], 0.f));
      }
    }
  }

  // ---- manual grid barrier (device-scope, cross-XCD safe) ----
  __syncthreads();
  if (tid == 0) {
    // release: drains vm + writes back dirty L2, then bumps the counter
    __hip_atomic_fetch_add(cnt, 1u, __ATOMIC_RELEASE, __HIP_MEMORY_SCOPE_AGENT);
    // spin RELAXED: performed at the coherent point, NO cache invalidate
    while (__hip_atomic_load(cnt, __ATOMIC_RELAXED, __HIP_MEMORY_SCOPE_AGENT)
           < (unsigned int)NBLOCKS) {
      __builtin_amdgcn_s_sleep(32);
    }
    // exactly one acquire: invalidate stale L1/L2 so phase 2 sees h1/h2
    (void)__hip_atomic_load(cnt, __ATOMIC_ACQUIRE, __HIP_MEMORY_SCOPE_AGENT);
  }
  __syncthreads();

  // ---- phase 2: edge (R8 structure) ----
  const int eq   = tid & 1;
  const int pair = tid >> 1;          // 0..255
  const int estride = NBLOCKS * (NTHREADS / 2);

  for (int e = bid * (NTHREADS / 2) + pair; e < n_edges; e += estride) {
    int src = edge_index[e];
    int dst = edge_index[n_edges + e];
    int t   = edge_type[e];

    F4H a, b, u, v;
    a.f = *reinterpret_cast<const float4*>(h1 + (size_t)src * L1_DIM + eq * 8);
    b.f = *reinterpret_cast<const float4*>(h2 + (size_t)dst * L1_DIM + eq * 8);
    u.f = *reinterpret_cast<const float4*>(wl + t * 32 + eq * 8);
    v.f = *reinterpret_cast<const float4*>(wl + t * 32 + 16 + eq * 8);

    float s = 0.f;
#if __has_builtin(__builtin_amdgcn_fdot2)
#pragma unroll
    for (int p = 0; p < 4; ++p) {
      s = __builtin_amdgcn_fdot2(a.h[p], u.h[p], s, false);
      s = __builtin_amdgcn_fdot2(b.h[p], v.h[p], s, false);
    }
#else
#pragma unroll
    for (int p = 0; p < 4; ++p) {
      float2 af = __half22float2(a.h[p]), uf = __half22float2(u.h[p]);
      float2 bf = __half22float2(b.h[p]), vf = __half22float2(v.h[p]);
      s = fmaf(af.x, uf.x, s); s = fmaf(af.y, uf.y, s);
      s = fmaf(bf.x, vf.x, s); s = fmaf(bf.y, vf.y, s);
    }
#endif

    s += __shfl_xor(s, 1);
    if (eq == 0) {
      out[e] = 1.0f / (1.0f + __expf(-s));
    }
  }
}

extern "C" void kernel_launch(void* const* d_in, const int* in_sizes, int n_in,
                              void* d_out, int out_size, void* d_ws, size_t ws_size,
                              hipStream_t stream) {
  const float* z      = (const float*)d_in[0];
  const int* edge_idx = (const int*)d_in[1];
  const int* edge_typ = (const int*)d_in[2];
  const float* w1_l1  = (const float*)d_in[3];
  const float* w1_l2  = (const float*)d_in[4];
  const float* w2_l1  = (const float*)d_in[5];
  const float* w2_l2  = (const float*)d_in[6];
  float* out = (float*)d_out;

  int n_nodes = in_sizes[0] / IN_DIM;
  int n_edges = in_sizes[2];
  int n_l2    = in_sizes[4];          // 1000*16

  __half* h1 = (__half*)d_ws;
  __half* h2 = h1 + (size_t)n_nodes * L1_DIM;
  unsigned int* cnt = (unsigned int*)(h2 + (size_t)n_nodes * L1_DIM);

  // reset barrier counter (graph-capturable memset node)
  hipMemsetAsync(cnt, 0, sizeof(unsigned int), stream);

  fused_kernel<<<NBLOCKS, NTHREADS, 0, stream>>>(
      z, w1_l1, w2_l1, w1_l2, w2_l2, edge_idx, edge_typ,
      h1, h2, cnt, out, n_nodes, n_edges, n_l2);
}

// Round 14
// 36.560 us; speedup vs baseline: 3.7056x; 2.5008x over previous
//
#include <hip/hip_runtime.h>
#include <hip/hip_fp16.h>
#include <math.h>

#define IN_DIM 256
#define L1_DIM 16
#define N_ETYPE_MAX 1000

typedef _Float16 f16x8 __attribute__((ext_vector_type(8)));
typedef float f32x4 __attribute__((ext_vector_type(4)));

union F4H { float4 f; __half2 h[4]; };

// ---------------- proj kernel (MFMA f16, R6/R8 structure, pure) ----------------
// GEMM M=n_nodes, N=32 ([w1|w2]), K=256 via mfma_f32_16x16x32_f16.
// Block = 256 = 4 waves, M=64 nodes/block, wave w owns rows 16w..16w+15.
// No LDS, no barrier: lane (q=l>>4, r=l&15) loads its A-fragment directly
// from global; B fragments (both weight tables) preloaded into VGPRs.
__global__ __launch_bounds__(256) void proj_kernel(
    const float* __restrict__ z,
    const float* __restrict__ w1,     // [256][16]
    const float* __restrict__ w2,
    __half* __restrict__ h1,          // [n_nodes][16] fp16
    __half* __restrict__ h2,
    int n_nodes) {
  const int tid  = (int)threadIdx.x;
  const int lane = tid & 63;
  const int wv   = tid >> 6;      // 0..3
  const int r    = lane & 15;     // A row-in-tile / B col / D col
  const int q    = lane >> 4;     // k-subgroup 0..3
  const int node0 = (int)blockIdx.x * 64;

  // ---- B fragments: k = 32s + 8q + j, col = r ----
  f16x8 bf1[8], bf2[8];
#pragma unroll
  for (int s = 0; s < 8; ++s) {
#pragma unroll
    for (int j = 0; j < 8; ++j) {
      int k = 32 * s + 8 * q + j;
      bf1[s][j] = (_Float16)w1[k * L1_DIM + r];
      bf2[s][j] = (_Float16)w2[k * L1_DIM + r];
    }
  }

  // ---- A row pointer (clamped for tail block) ----
  int arow = node0 + wv * 16 + r;
  int ar = arow < n_nodes ? arow : (n_nodes - 1);
  const float* zrow = z + (size_t)ar * IN_DIM + 8 * q;

  f32x4 acc1 = {0.f, 0.f, 0.f, 0.f};
  f32x4 acc2 = {0.f, 0.f, 0.f, 0.f};

#pragma unroll
  for (int s = 0; s < 8; ++s) {
    float4 lo = *reinterpret_cast<const float4*>(zrow + 32 * s);
    float4 hi = *reinterpret_cast<const float4*>(zrow + 32 * s + 4);
    f16x8 af;
    af[0] = (_Float16)lo.x; af[1] = (_Float16)lo.y;
    af[2] = (_Float16)lo.z; af[3] = (_Float16)lo.w;
    af[4] = (_Float16)hi.x; af[5] = (_Float16)hi.y;
    af[6] = (_Float16)hi.z; af[7] = (_Float16)hi.w;
    acc1 = __builtin_amdgcn_mfma_f32_16x16x32_f16(af, bf1[s], acc1, 0, 0, 0);
    acc2 = __builtin_amdgcn_mfma_f32_16x16x32_f16(af, bf2[s], acc2, 0, 0, 0);
  }

  // ---- D layout: col = r, row = 4q + i -> node = node0 + 16wv + 4q + i ----
#pragma unroll
  for (int i = 0; i < 4; ++i) {
    int node = node0 + wv * 16 + 4 * q + i;
    if (node < n_nodes) {
      h1[(size_t)node * L1_DIM + r] = __float2half(fmaxf(acc1[i], 0.f));
      h2[(size_t)node * L1_DIM + r] = __float2half(fmaxf(acc2[i], 0.f));
    }
  }
}

// ---------------- edge kernel (R8 structure, doubled occupancy) ----------------
// 1024 threads + 62.5 KB LDS -> still 2 blocks/CU but 32 waves/CU (100%
// occupancy, 2x R8) for the latency-bound gather loop. launch_bounds(1024,8)
// pins VGPR <= 64 so 2 blocks/CU is guaranteed. Stages wl DIRECTLY from the
// f32 tables (L2-hot; kills the wq intermediate + proj's convert tail).
// Per edge: 2 lanes (q owns row-half q), 2 VMEM gathers + 2 ds_read_b128,
// 8x fdot2, shfl_xor(1), even lane stores sigmoid.
__global__ __launch_bounds__(1024, 8) void edge_kernel(
    const int* __restrict__ edge_index,  // [2][n_edges]
    const int* __restrict__ edge_type,   // [n_edges]
    const __half* __restrict__ h1,
    const __half* __restrict__ h2,
    const float* __restrict__ w1_l2,     // [1000][16] f32
    const float* __restrict__ w2_l2,
    float* __restrict__ out,
    int n_edges, int n_l2) {
  __shared__ __align__(16) __half wl[N_ETYPE_MAX * 32];  // 62.5 KB

  const int tid = (int)threadIdx.x;

  // stage + convert interleaved fp16 table from f32 sources (coalesced)
  for (int i = tid; i < n_l2; i += 1024) {
    int t = i >> 4;
    int j = i & 15;
    wl[t * 32 + j]      = __float2half(w1_l2[i]);
    wl[t * 32 + 16 + j] = __float2half(w2_l2[i]);
  }
  __syncthreads();

  const int q = tid & 1;
  const int pair = tid >> 1;          // 0..511
  const int stride = (int)gridDim.x * 512;

  for (int e = (int)blockIdx.x * 512 + pair; e < n_edges; e += stride) {
    int src = edge_index[e];
    int dst = edge_index[n_edges + e];
    int t   = edge_type[e];

    F4H a, b, u, v;
    a.f = *reinterpret_cast<const float4*>(h1 + (size_t)src * L1_DIM + q * 8);
    b.f = *reinterpret_cast<const float4*>(h2 + (size_t)dst * L1_DIM + q * 8);
    u.f = *reinterpret_cast<const float4*>(wl + t * 32 + q * 8);
    v.f = *reinterpret_cast<const float4*>(wl + t * 32 + 16 + q * 8);

    float s = 0.f;
#if __has_builtin(__builtin_amdgcn_fdot2)
#pragma unroll
    for (int p = 0; p < 4; ++p) {
      s = __builtin_amdgcn_fdot2(a.h[p], u.h[p], s, false);
      s = __builtin_amdgcn_fdot2(b.h[p], v.h[p], s, false);
    }
#else
#pragma unroll
    for (int p = 0; p < 4; ++p) {
      float2 af = __half22float2(a.h[p]), uf = __half22float2(u.h[p]);
      float2 bf = __half22float2(b.h[p]), vf = __half22float2(v.h[p]);
      s = fmaf(af.x, uf.x, s); s = fmaf(af.y, uf.y, s);
      s = fmaf(bf.x, vf.x, s); s = fmaf(bf.y, vf.y, s);
    }
#endif

    s += __shfl_xor(s, 1);
    if (q == 0) {
      out[e] = 1.0f / (1.0f + __expf(-s));
    }
  }
}

extern "C" void kernel_launch(void* const* d_in, const int* in_sizes, int n_in,
                              void* d_out, int out_size, void* d_ws, size_t ws_size,
                              hipStream_t stream) {
  const float* z      = (const float*)d_in[0];
  const int* edge_idx = (const int*)d_in[1];
  const int* edge_typ = (const int*)d_in[2];
  const float* w1_l1  = (const float*)d_in[3];
  const float* w1_l2  = (const float*)d_in[4];
  const float* w2_l1  = (const float*)d_in[5];
  const float* w2_l2  = (const float*)d_in[6];
  float* out = (float*)d_out;

  int n_nodes = in_sizes[0] / IN_DIM;
  int n_edges = in_sizes[2];
  int n_l2    = in_sizes[4];          // 1000*16

  __half* h1 = (__half*)d_ws;
  __half* h2 = h1 + (size_t)n_nodes * L1_DIM;

  {
    int grid = (n_nodes + 63) / 64;   // 782
    proj_kernel<<<grid, 256, 0, stream>>>(z, w1_l1, w2_l1, h1, h2, n_nodes);
  }
  {
    // 512 blocks x 512 pairs, grid-stride over 1M edges
    edge_kernel<<<512, 1024, 0, stream>>>(edge_idx, edge_typ, h1, h2,
                                          w1_l2, w2_l2, out, n_edges, n_l2);
  }
}

// Round 16
// 36.391 us; speedup vs baseline: 3.7228x; 1.0047x over previous
//
#include <hip/hip_runtime.h>
#include <hip/hip_fp16.h>
#include <math.h>

#define IN_DIM 256
#define L1_DIM 16
#define N_ETYPE_MAX 1000
#define ZROW 264   // halfs per LDS row: 256 data + 8 pad (row = 528 B, 16B-aligned)

typedef _Float16 f16x8 __attribute__((ext_vector_type(8)));
typedef float f32x4 __attribute__((ext_vector_type(4)));

union F4H { float4 f; __half2 h[4]; };

// ---------------- proj kernel (MFMA f16 + LDS-staged tile) ----------------
// z tile (64 rows x 1KB f32) staged into LDS with FLAT-CONTIGUOUS float4
// loads (lane-adjacent 16B -> pure sequential HBM bursts), converted to f16
// (33 KB LDS, ZROW=264: 256 data halfs + 8 pad). One barrier. Fragments via
// ds_read_b128. R15 bug: ZROW=136 sized rows for 128 halfs but a z row is
// 256 halfs -> OOB. Fixed here; structure otherwise identical.
// Trailing 8 blocks build interleaved fp16 wq for the edge kernel.
__global__ __launch_bounds__(256) void proj_kernel(
    const float* __restrict__ z,
    const float* __restrict__ w1,     // [256][16]
    const float* __restrict__ w2,
    const float* __restrict__ w1_l2,  // [1000][16]
    const float* __restrict__ w2_l2,
    __half* __restrict__ h1,          // [n_nodes][16] fp16
    __half* __restrict__ h2,
    __half* __restrict__ wq,          // [n_types][32] interleaved fp16
    int n_nodes, int n_l2, int nblocks_proj) {
  // trailing blocks: build interleaved fp16 level-2 table
  if ((int)blockIdx.x >= nblocks_proj) {
    int t0 = ((int)blockIdx.x - nblocks_proj) * 256 + (int)threadIdx.x;
    for (int i = t0; i < n_l2; i += 8 * 256) {
      int t = i >> 4;
      int j = i & 15;
      wq[t * 32 + j]      = __float2half(w1_l2[i]);
      wq[t * 32 + 16 + j] = __float2half(w2_l2[i]);
    }
    return;
  }

  __shared__ __align__(16) __half zs[64 * ZROW];   // 33.8 KB

  const int tid  = (int)threadIdx.x;
  const int node0 = (int)blockIdx.x * 64;

  // ---- stage: 16 flat-contiguous float4 loads/thread, cvt f32->f16 ----
  // slot = rr*256 + tid: byte address slot*16 -> consecutive lanes are
  // 16B-adjacent (1 KB sequential burst per wave instruction).
#pragma unroll
  for (int rr = 0; rr < 16; ++rr) {
    int slot = rr * 256 + tid;       // 0..4095
    int row  = slot >> 6;            // 64 float4 per 1KB f32 row
    int c4   = slot & 63;            // halfs columns 4*c4 .. 4*c4+3
    int ng = node0 + row;
    if (ng >= n_nodes) ng = n_nodes - 1;   // clamp (tail block only)
    float4 v = *reinterpret_cast<const float4*>(z + (size_t)ng * IN_DIM + c4 * 4);
    __half2* p = reinterpret_cast<__half2*>(zs + row * ZROW + c4 * 4);
    p[0] = __floats2half2_rn(v.x, v.y);
    p[1] = __floats2half2_rn(v.z, v.w);
  }

  // ---- B fragments (issued while staging drains): k = 32s+8q+j, col r ----
  const int lane = tid & 63;
  const int wv   = tid >> 6;      // 0..3
  const int r    = lane & 15;     // A row-in-tile / B col / D col
  const int q    = lane >> 4;     // k-subgroup 0..3

  f16x8 bf1[8], bf2[8];
#pragma unroll
  for (int s = 0; s < 8; ++s) {
#pragma unroll
    for (int j = 0; j < 8; ++j) {
      int k = 32 * s + 8 * q + j;
      bf1[s][j] = (_Float16)w1[k * L1_DIM + r];
      bf2[s][j] = (_Float16)w2[k * L1_DIM + r];
    }
  }

  __syncthreads();

  // ---- compute: fragment = ds_read_b128, 16 MFMA ----
  f32x4 acc1 = {0.f, 0.f, 0.f, 0.f};
  f32x4 acc2 = {0.f, 0.f, 0.f, 0.f};

  const __half* zrow = zs + (wv * 16 + r) * ZROW + 8 * q;
#pragma unroll
  for (int s = 0; s < 8; ++s) {
    f16x8 af = *reinterpret_cast<const f16x8*>(zrow + 32 * s);  // 16B aligned
    acc1 = __builtin_amdgcn_mfma_f32_16x16x32_f16(af, bf1[s], acc1, 0, 0, 0);
    acc2 = __builtin_amdgcn_mfma_f32_16x16x32_f16(af, bf2[s], acc2, 0, 0, 0);
  }

  // ---- D layout: col = r, row = 4q + i -> node = node0 + 16wv + 4q + i ----
#pragma unroll
  for (int i = 0; i < 4; ++i) {
    int node = node0 + wv * 16 + 4 * q + i;
    if (node < n_nodes) {
      h1[(size_t)node * L1_DIM + r] = __float2half(fmaxf(acc1[i], 0.f));
      h2[(size_t)node * L1_DIM + r] = __float2half(fmaxf(acc2[i], 0.f));
    }
  }
}

// ---------------- edge kernel (R8 structure + nontemporal idx/out) --------
// 2 lanes per edge (q = tid&1 owns row-half q). Per lane: 2 VMEM gathers
// (h1[src], h2[dst]) + 2 ds_read_b128 from the LDS-staged fp16 w table.
// idx loads and out stores are NONTEMPORAL so the 16 MB of streaming data
// doesn't evict the 3.2 MB h gather set from L2.
__global__ __launch_bounds__(512) void edge_kernel(
    const int* __restrict__ edge_index,  // [2][n_edges]
    const int* __restrict__ edge_type,   // [n_edges]
    const __half* __restrict__ h1,
    const __half* __restrict__ h2,
    const __half* __restrict__ wq,       // [1000][32] interleaved fp16
    float* __restrict__ out,
    int n_edges, int n_types) {
  __shared__ __align__(16) __half wl[N_ETYPE_MAX * 32];  // 62.5 KB

  const int tid = (int)threadIdx.x;

  // stage interleaved fp16 w table (coalesced float4 copies)
  {
    const float4* srcp = reinterpret_cast<const float4*>(wq);
    float4* dstp = reinterpret_cast<float4*>(wl);
    int nf4 = n_types * 4;  // 32 halfs = 4 float4 per type
    for (int i = tid; i < nf4; i += 512) dstp[i] = srcp[i];
  }
  __syncthreads();

  const int q = tid & 1;
  const int pair = tid >> 1;          // 0..255
  const int stride = (int)gridDim.x * 256;

  for (int e = (int)blockIdx.x * 256 + pair; e < n_edges; e += stride) {
    int src = __builtin_nontemporal_load(edge_index + e);
    int dst = __builtin_nontemporal_load(edge_index + n_edges + e);
    int t   = __builtin_nontemporal_load(edge_type + e);

    F4H a, b, u, v;
    a.f = *reinterpret_cast<const float4*>(h1 + (size_t)src * L1_DIM + q * 8);
    b.f = *reinterpret_cast<const float4*>(h2 + (size_t)dst * L1_DIM + q * 8);
    u.f = *reinterpret_cast<const float4*>(wl + t * 32 + q * 8);
    v.f = *reinterpret_cast<const float4*>(wl + t * 32 + 16 + q * 8);

    float s = 0.f;
#if __has_builtin(__builtin_amdgcn_fdot2)
#pragma unroll
    for (int p = 0; p < 4; ++p) {
      s = __builtin_amdgcn_fdot2(a.h[p], u.h[p], s, false);
      s = __builtin_amdgcn_fdot2(b.h[p], v.h[p], s, false);
    }
#else
#pragma unroll
    for (int p = 0; p < 4; ++p) {
      float2 af = __half22float2(a.h[p]), uf = __half22float2(u.h[p]);
      float2 bf = __half22float2(b.h[p]), vf = __half22float2(v.h[p]);
      s = fmaf(af.x, uf.x, s); s = fmaf(af.y, uf.y, s);
      s = fmaf(bf.x, vf.x, s); s = fmaf(bf.y, vf.y, s);
    }
#endif

    s += __shfl_xor(s, 1);
    if (q == 0) {
      float o = 1.0f / (1.0f + __expf(-s));
      __builtin_nontemporal_store(o, out + e);
    }
  }
}

extern "C" void kernel_launch(void* const* d_in, const int* in_sizes, int n_in,
                              void* d_out, int out_size, void* d_ws, size_t ws_size,
                              hipStream_t stream) {
  const float* z      = (const float*)d_in[0];
  const int* edge_idx = (const int*)d_in[1];
  const int* edge_typ = (const int*)d_in[2];
  const float* w1_l1  = (const float*)d_in[3];
  const float* w1_l2  = (const float*)d_in[4];
  const float* w2_l1  = (const float*)d_in[5];
  const float* w2_l2  = (const float*)d_in[6];
  float* out = (float*)d_out;

  int n_nodes = in_sizes[0] / IN_DIM;
  int n_edges = in_sizes[2];
  int n_l2    = in_sizes[4];          // 1000*16
  int n_types = n_l2 / L1_DIM;        // 1000

  __half* h1 = (__half*)d_ws;
  __half* h2 = h1 + (size_t)n_nodes * L1_DIM;
  __half* wq = h2 + (size_t)n_nodes * L1_DIM;   // [n_types][32]

  {
    int nblocks_proj = (n_nodes + 63) / 64;   // 782
    int grid = nblocks_proj + 8;              // +8 blocks: build wq
    proj_kernel<<<grid, 256, 0, stream>>>(z, w1_l1, w2_l1, w1_l2, w2_l2,
                                          h1, h2, wq,
                                          n_nodes, n_l2, nblocks_proj);
  }
  {
    edge_kernel<<<512, 512, 0, stream>>>(edge_idx, edge_typ, h1, h2, wq,
                                         out, n_edges, n_types);
  }
}